// Round 5
// baseline (500.030 us; speedup 1.0000x reference)
//
#include <hip/hip_runtime.h>
#include <hip/hip_bf16.h>
#include <stdint.h>
#include <type_traits>

typedef unsigned short ushort_t;
typedef __bf16 bf16x8 __attribute__((ext_vector_type(8)));
typedef unsigned short u16x8 __attribute__((ext_vector_type(8)));
typedef float f32x4 __attribute__((ext_vector_type(4)));

#define MFMA_BF16(a, b, c) __builtin_amdgcn_mfma_f32_16x16x32_bf16((a), (b), (c), 0, 0, 0)

#define GLD_LDS(gptr, lptr) \
    __builtin_amdgcn_global_load_lds((const __attribute__((address_space(1))) void*)(gptr), \
                                     (__attribute__((address_space(3))) void*)(lptr), 16, 0, 0)

static __device__ __forceinline__ float bf2f(__hip_bfloat16 x) { return __bfloat162float(x); }
static __device__ __forceinline__ ushort_t f2bfbits(float f) {
    __hip_bfloat16 h = __float2bfloat16(f);
    return *(ushort_t*)&h;
}

template <typename T>
static __device__ __forceinline__ void storeT(T* p, float v);
template <>
__device__ __forceinline__ void storeT<float>(float* p, float v) { *p = v; }
template <>
__device__ __forceinline__ void storeT<__hip_bfloat16>(__hip_bfloat16* p, float v) {
    *p = __float2bfloat16(v);
}

// ---------------------------------------------------------------------------
// dtype probe + bias/slope pre-convert (as round 3/4).
// ---------------------------------------------------------------------------
__global__ void detect_kernel(const ushort_t* __restrict__ X,
                              const void* bq, const void* bk, const void* bv,
                              const void* bo, const void* slopes,
                              int* flag, float* slopesF, float* bqF,
                              float* bkF, float* bvF, float* boF) {
    __shared__ int cnt_s;
    if (threadIdx.x == 0) cnt_s = 0;
    __syncthreads();
    int cnt = 0;
    for (int i = threadIdx.x; i < 8192; i += 256) {
        ushort_t u = X[2 * i];
        int ex = (u >> 7) & 0xFF;
        if (ex >= 0xC0) cnt++;
    }
    for (int off = 1; off < 64; off <<= 1) cnt += __shfl_xor(cnt, off);
    if ((threadIdx.x & 63) == 0) atomicAdd(&cnt_s, cnt);
    __syncthreads();
    const bool f32 = cnt_s > 100;
    if (threadIdx.x == 0) *flag = f32 ? 1 : 0;
    auto conv = [&](const void* src, float* dst, int n) {
        for (int i = threadIdx.x; i < n; i += 256)
            dst[i] = f32 ? ((const float*)src)[i]
                         : __bfloat162float(((const __hip_bfloat16*)src)[i]);
    };
    conv(bq, bqF, 2048);
    conv(bk, bkF, 512);
    conv(bv, bvF, 512);
    conv(bo, boF, 2048);
    conv(slopes, slopesF, 32);
}

// ---------------------------------------------------------------------------
// Bulk dtype convert (fp32->bf16 or bf16 copy).
// ---------------------------------------------------------------------------
__global__ __launch_bounds__(256) void cvt_kernel(const int* __restrict__ flag,
                                                  const void* __restrict__ src,
                                                  ushort_t* __restrict__ dst, int n4) {
    const bool f32 = (*flag == 1);
    const int stride = gridDim.x * 256;
    for (int i = blockIdx.x * 256 + threadIdx.x; i < n4; i += stride) {
        if (f32) {
            float4 f = ((const float4*)src)[i];
            ((ushort4*)dst)[i] =
                make_ushort4(f2bfbits(f.x), f2bfbits(f.y), f2bfbits(f.z), f2bfbits(f.w));
        } else {
            ((ushort4*)dst)[i] = ((const ushort4*)src)[i];
        }
    }
}

// ---------------------------------------------------------------------------
// Tile staging into bf16 LDS [128][64] with XOR column-chunk swizzle:
// element (row, chunk c of 8 shorts) lives at LDS[row*64 + (c ^ (row&7))*8].
// Breaks the stride-64 16-way ds_read_b128 bank conflicts; global coalescing
// unchanged (per-lane permutation within the same 128B segment).
// ---------------------------------------------------------------------------
__device__ __forceinline__ void stage_tile(const __hip_bfloat16* __restrict__ M, int K,
                                           int k0, ushort_t* lds, int tid) {
    const int wave = tid >> 6, lane = tid & 63;
    const int srow = lane >> 3;                      // 0..7 within chunk
    const int scol = ((lane & 7) ^ srow) * 8;        // swizzled source column
#pragma unroll
    for (int t = 0; t < 4; ++t) {
        const int chunk = wave * 4 + t;  // 16 chunks x 8 rows
        GLD_LDS((const ushort_t*)M + (size_t)(chunk * 8 + srow) * K + k0 + scol,
                lds + chunk * 512);
    }
}

__device__ __forceinline__ void stage_tile(const float* __restrict__ M, int K,
                                           int k0, ushort_t* lds, int tid) {
#pragma unroll
    for (int q = 0; q < 8; ++q) {
        const int idx = q * 256 + tid;   // 0..2047 float4s
        const int row = idx >> 4;
        const int c4 = (idx & 15) * 4;   // float col within 64
        float4 f = *(const float4*)(M + (size_t)row * K + k0 + c4);
        const int dcol = (((c4 >> 3) ^ (row & 7)) * 8) + (c4 & 7);
        *(ushort4*)(lds + row * 64 + dcol) =
            make_ushort4(f2bfbits(f.x), f2bfbits(f.y), f2bfbits(f.z), f2bfbits(f.w));
    }
}

// ---------------------------------------------------------------------------
// 128x128xK GEMM tile (swizzled LDS reads).
// ---------------------------------------------------------------------------
template <typename TA, typename TW, typename TC>
__device__ __forceinline__ void gemm_tile(const TA* __restrict__ A,
                                          const TW* __restrict__ W,
                                          const float* __restrict__ biasF,
                                          TC* __restrict__ C, int K, int ldc) {
    __shared__ __align__(16) ushort_t As[128 * 64];
    __shared__ __align__(16) ushort_t Bs[128 * 64];
    const int tid = threadIdx.x;
    const int wave = tid >> 6, lane = tid & 63;
    const int quad = lane >> 4, l15 = lane & 15;
    const int wm = (wave >> 1) * 64, wn = (wave & 1) * 64;
    const int sw = l15 & 7;  // row-based swizzle key (wm/wn/mi*16 are mult of 8)

    f32x4 acc[4][4];
#pragma unroll
    for (int i = 0; i < 4; ++i)
#pragma unroll
        for (int j = 0; j < 4; ++j) acc[i][j] = {0.f, 0.f, 0.f, 0.f};

    for (int k0 = 0; k0 < K; k0 += 64) {
        stage_tile(A, K, k0, As, tid);
        stage_tile(W, K, k0, Bs, tid);
        __syncthreads();
#pragma unroll
        for (int kk = 0; kk < 2; ++kk) {
            const int chs = ((kk * 4 + quad) ^ sw) * 8;  // swizzled chunk offset
            bf16x8 af[4], bfr[4];
#pragma unroll
            for (int mi = 0; mi < 4; ++mi)
                af[mi] = *(const bf16x8*)(As + (wm + mi * 16 + l15) * 64 + chs);
#pragma unroll
            for (int ni = 0; ni < 4; ++ni)
                bfr[ni] = *(const bf16x8*)(Bs + (wn + ni * 16 + l15) * 64 + chs);
#pragma unroll
            for (int mi = 0; mi < 4; ++mi)
#pragma unroll
                for (int ni = 0; ni < 4; ++ni)
                    acc[mi][ni] = MFMA_BF16(af[mi], bfr[ni], acc[mi][ni]);
        }
        __syncthreads();
    }
#pragma unroll
    for (int mi = 0; mi < 4; ++mi) {
#pragma unroll
        for (int ni = 0; ni < 4; ++ni) {
            const int col = wn + ni * 16 + l15;
            const float bv = biasF[col];
#pragma unroll
            for (int r = 0; r < 4; ++r) {
                const int row = wm + mi * 16 + quad * 4 + r;
                storeT(C + (size_t)row * ldc + col, acc[mi][ni][r] + bv);
            }
        }
    }
}

// ======================== FAST PATH (pure-bf16 GEMMs) =======================
__global__ __launch_bounds__(256, 2) void qkv_fast(
    const __hip_bfloat16* __restrict__ X,
    const __hip_bfloat16* __restrict__ Wq, const __hip_bfloat16* __restrict__ Wk,
    const __hip_bfloat16* __restrict__ Wv, const float* __restrict__ bqF,
    const float* __restrict__ bkF, const float* __restrict__ bvF,
    __hip_bfloat16* __restrict__ Qb, __hip_bfloat16* __restrict__ Kb,
    __hip_bfloat16* __restrict__ Vb) {
    const int nt = blockIdx.x, mt = blockIdx.y;
    const __hip_bfloat16* W;
    const float* bias;
    __hip_bfloat16* C;
    int ldc, colbase;
    if (nt < 16)      { W = Wq; bias = bqF; C = Qb; ldc = 2048; colbase = nt * 128; }
    else if (nt < 20) { W = Wk; bias = bkF; C = Kb; ldc = 512;  colbase = (nt - 16) * 128; }
    else              { W = Wv; bias = bvF; C = Vb; ldc = 512;  colbase = (nt - 20) * 128; }
    gemm_tile(X + (size_t)mt * 128 * 2048, W + (size_t)colbase * 2048, bias + colbase,
              C + (size_t)mt * 128 * ldc + colbase, 2048, ldc);
}

__global__ __launch_bounds__(256, 2) void oproj_fast(
    const __hip_bfloat16* __restrict__ A, const __hip_bfloat16* __restrict__ Wo,
    const float* __restrict__ boF, float* __restrict__ C) {
    gemm_tile(A + (size_t)blockIdx.y * 128 * 2048,
              Wo + (size_t)blockIdx.x * 128 * 2048, boF + blockIdx.x * 128,
              C + (size_t)blockIdx.y * 128 * 2048 + blockIdx.x * 128, 2048, 2048);
}

// ---------------------------------------------------------------------------
// V transpose: Vb[b*2048+s][hkv*64+dh] -> Vt[(b*8+hkv)*64+dh][s] (bf16).
// 1024 blocks x 256. Reads coalesced (128B per wave instr), writes b128.
// ---------------------------------------------------------------------------
__global__ __launch_bounds__(256) void vtrans_kernel(const ushort_t* __restrict__ Vb,
                                                     ushort_t* __restrict__ Vt) {
    const int blk = blockIdx.x;
    const int bh = blk >> 6;        // b*8 + hkv
    const int sc = blk & 63;        // 64 s-chunks of 32
    const int tid = threadIdx.x;
    const int dh = tid & 63;
    const int s0 = sc * 32 + (tid >> 6) * 8;
    const int b = bh >> 3, hkv = bh & 7;
    u16x8 vv;
#pragma unroll
    for (int e = 0; e < 8; ++e)
        vv[e] = Vb[((size_t)(b * 2048 + s0 + e)) * 512 + hkv * 64 + dh];
    *(u16x8*)(Vt + ((size_t)(bh * 64 + dh)) * 2048 + s0) = vv;
}

// ==================== FALLBACK PATH GEMMs (round-3 style) ===================
template <bool F32>
__global__ __launch_bounds__(256, 2) void qkv_kernel(
    const int* __restrict__ flag, const void* __restrict__ Xv,
    const void* __restrict__ Wqv, const void* __restrict__ Wkv,
    const void* __restrict__ Wvv, const float* __restrict__ bqF,
    const float* __restrict__ bkF, const float* __restrict__ bvF,
    __hip_bfloat16* __restrict__ Qb, __hip_bfloat16* __restrict__ Kb,
    __hip_bfloat16* __restrict__ Vb) {
    if ((*flag == 1) != F32) return;
    using T = typename std::conditional<F32, float, __hip_bfloat16>::type;
    const T* X = (const T*)Xv;
    const int nt = blockIdx.x, mt = blockIdx.y;
    const T* W;
    const float* bias;
    __hip_bfloat16* C;
    int ldc, colbase;
    if (nt < 16)      { W = (const T*)Wqv; bias = bqF; C = Qb; ldc = 2048; colbase = nt * 128; }
    else if (nt < 20) { W = (const T*)Wkv; bias = bkF; C = Kb; ldc = 512;  colbase = (nt - 16) * 128; }
    else              { W = (const T*)Wvv; bias = bvF; C = Vb; ldc = 512;  colbase = (nt - 20) * 128; }
    gemm_tile(X + (size_t)mt * 128 * 2048, W + (size_t)colbase * 2048, bias + colbase,
              C + (size_t)mt * 128 * ldc + colbase, 2048, ldc);
}

template <bool F32>
__global__ __launch_bounds__(256, 2) void oproj_kernel(
    const int* __restrict__ flag, const __hip_bfloat16* __restrict__ A,
    const void* __restrict__ Wov, const float* __restrict__ boF,
    float* __restrict__ C) {
    if ((*flag == 1) != F32) return;
    using T = typename std::conditional<F32, float, __hip_bfloat16>::type;
    gemm_tile(A + (size_t)blockIdx.y * 128 * 2048,
              (const T*)Wov + (size_t)blockIdx.x * 128 * 2048, boF + blockIdx.x * 128,
              C + (size_t)blockIdx.y * 128 * 2048 + blockIdx.x * 128, 2048, 2048);
}

// ---------------------------------------------------------------------------
// Flash attention v2: barrier-free. One block per (b,h,64-row q-tile);
// 4 waves, each owning 16 q-rows with a private 16x64 P region in LDS
// (XOR-swizzled, conflict-free b128 reads). K and V^T fragments stream
// straight from global (L1/L2-resident tiles). Log2-domain softmax; masked
// score = -3e38 so exp2 underflows to 0 (no guard cndmask needed).
// ---------------------------------------------------------------------------
__global__ __launch_bounds__(256, 4) void attn2_kernel(
    const __hip_bfloat16* __restrict__ Qg, const __hip_bfloat16* __restrict__ Kg,
    const ushort_t* __restrict__ Vt, const float* __restrict__ slopesF,
    __hip_bfloat16* __restrict__ Og) {
    constexpr int S = 2048, WIN = 1024;
    constexpr float LOG2E = 1.44269504f;
    constexpr float SCALE2 = 0.125f * LOG2E;   // log2-domain scale
    constexpr float NEGBIG = -3e38f;
    __shared__ __align__(16) ushort_t P_lds[4 * 16 * 64];  // per-wave 2KB

    const int tile = blockIdx.x;
    const int qt = tile & 31;
    const int h = (tile >> 5) & 31;
    const int b = tile >> 10;
    const int i0 = qt * 64;
    const int hkv = h >> 2;
    const int bh = b * 8 + hkv;
    const int tid = threadIdx.x;
    const int wave = tid >> 6, lane = tid & 63;
    const int quad = lane >> 4, l15 = lane & 15;
    const int sw = l15 & 7;
    const float slope2 = slopesF[h] * LOG2E;
    ushort_t* Pw = P_lds + wave * 1024;

    // Q fragments (A-layout) for this wave's 16 rows
    const int qrow = i0 + wave * 16 + l15;
    const __hip_bfloat16* qbase = Qg + ((size_t)(b * S + qrow)) * 2048 + h * 64;
    bf16x8 aq[2];
    aq[0] = *(const bf16x8*)(qbase + quad * 8);
    aq[1] = *(const bf16x8*)(qbase + 32 + quad * 8);

    f32x4 oacc[4];
#pragma unroll
    for (int ni = 0; ni < 4; ++ni) oacc[ni] = {0.f, 0.f, 0.f, 0.f};
    float m_i[4], l_i[4];
#pragma unroll
    for (int r = 0; r < 4; ++r) { m_i[r] = -1e30f; l_i[r] = 0.f; }

    const ushort_t* vbase = Vt + ((size_t)bh * 64) * 2048;
    const int iw = i0 + wave * 16 + quad * 4;  // this lane's first q-row

    const int jt_lo = (i0 - WIN + 1) > 0 ? ((i0 - WIN + 1) >> 6) : 0;
    for (int jt = jt_lo; jt <= qt; ++jt) {
        const int j0 = jt * 64;
        // ---- S = Q K^T ----
        f32x4 sacc[4];
#pragma unroll
        for (int ni = 0; ni < 4; ++ni) sacc[ni] = {0.f, 0.f, 0.f, 0.f};
#pragma unroll
        for (int kk = 0; kk < 2; ++kk) {
#pragma unroll
            for (int ni = 0; ni < 4; ++ni) {
                bf16x8 bkf = *(const bf16x8*)(Kg + ((size_t)(b * S + j0 + ni * 16 + l15)) * 512 +
                                              hkv * 64 + kk * 32 + quad * 8);
                sacc[ni] = MFMA_BF16(aq[kk], bkf, sacc[ni]);
            }
        }
        // ---- online softmax (log2 domain) ----
#pragma unroll
        for (int r = 0; r < 4; ++r) {
            const int i = iw + r;
            float sv[4];
#pragma unroll
            for (int ni = 0; ni < 4; ++ni) {
                const int rel = (j0 + ni * 16 + l15) - i;  // j - i, valid iff -WIN < rel <= 0
                float s = fmaf(sacc[ni][r], SCALE2, slope2 * (float)rel);
                sv[ni] = ((unsigned)(-rel) < (unsigned)WIN) ? s : NEGBIG;
            }
            float rowmax = fmaxf(fmaxf(sv[0], sv[1]), fmaxf(sv[2], sv[3]));
#pragma unroll
            for (int off = 1; off < 16; off <<= 1)
                rowmax = fmaxf(rowmax, __shfl_xor(rowmax, off));
            const float mn = fmaxf(m_i[r], rowmax);
            const float alpha = exp2f(m_i[r] - mn);
            m_i[r] = mn;
            float p0 = exp2f(sv[0] - mn), p1 = exp2f(sv[1] - mn);
            float p2 = exp2f(sv[2] - mn), p3 = exp2f(sv[3] - mn);
            const int rl = quad * 4 + r;  // local row 0..15
            const int base = rl * 64 + (l15 & 7);
            const int swr = rl & 7;
            Pw[base + (((0 * 2 + (l15 >> 3)) ^ swr) * 8)] = f2bfbits(p0);
            Pw[base + (((1 * 2 + (l15 >> 3)) ^ swr) * 8)] = f2bfbits(p1);
            Pw[base + (((2 * 2 + (l15 >> 3)) ^ swr) * 8)] = f2bfbits(p2);
            Pw[base + (((3 * 2 + (l15 >> 3)) ^ swr) * 8)] = f2bfbits(p3);
            float rowsum = (p0 + p1) + (p2 + p3);
#pragma unroll
            for (int off = 1; off < 16; off <<= 1) rowsum += __shfl_xor(rowsum, off);
            l_i[r] = l_i[r] * alpha + rowsum;
#pragma unroll
            for (int ni = 0; ni < 4; ++ni) oacc[ni][r] *= alpha;
        }
        // ---- O += P @ V (A = own P rows from LDS, B = V^T from global) ----
#pragma unroll
        for (int kk = 0; kk < 2; ++kk) {
            bf16x8 ap = *(const bf16x8*)(Pw + l15 * 64 + (((kk * 4 + quad) ^ sw) * 8));
#pragma unroll
            for (int ni = 0; ni < 4; ++ni) {
                bf16x8 bvf = *(const bf16x8*)(vbase + ((size_t)(ni * 16 + l15)) * 2048 +
                                              j0 + kk * 32 + quad * 8);
                oacc[ni] = MFMA_BF16(ap, bvf, oacc[ni]);
            }
        }
    }
    // epilogue
#pragma unroll
    for (int ni = 0; ni < 4; ++ni) {
#pragma unroll
        for (int r = 0; r < 4; ++r) {
            const int srow = iw + r;
            const float v = oacc[ni][r] / l_i[r];
            Og[((size_t)(b * S + srow)) * 2048 + h * 64 + ni * 16 + l15] = __float2bfloat16(v);
        }
    }
}

// ---------------------------------------------------------------------------
// Fallback attention (round-3 proven; used when ws too small for fast path).
// ---------------------------------------------------------------------------
__global__ __launch_bounds__(256, 2) void attn_kernel(
    const __hip_bfloat16* __restrict__ Qg, const __hip_bfloat16* __restrict__ Kg,
    const __hip_bfloat16* __restrict__ Vg, const float* __restrict__ slopesF,
    __hip_bfloat16* __restrict__ Og) {
    constexpr int S = 2048, WIN = 1024;
    constexpr float SCALE = 0.125f;
    constexpr float LOG2E = 1.44269504f;
    __shared__ __align__(16) ushort_t P_lds[64 * 72];
    __shared__ __align__(16) ushort_t Vt[64 * 72];

    const int tile = blockIdx.x;
    const int qt = tile & 31;
    const int h = (tile >> 5) & 31;
    const int b = tile >> 10;
    const int i0 = qt * 64;
    const int hkv = h >> 2;
    const int tid = threadIdx.x;
    const int wave = tid >> 6, lane = tid & 63;
    const int quad = lane >> 4, l15 = lane & 15;
    const float slope = slopesF[h];

    const int qrow = i0 + wave * 16 + l15;
    const __hip_bfloat16* qbase = Qg + ((size_t)(b * S + qrow)) * 2048 + h * 64;
    bf16x8 aq[2];
    aq[0] = *(const bf16x8*)(qbase + quad * 8);
    aq[1] = *(const bf16x8*)(qbase + 32 + quad * 8);

    f32x4 oacc[4];
#pragma unroll
    for (int ni = 0; ni < 4; ++ni) oacc[ni] = {0.f, 0.f, 0.f, 0.f};
    float m_i[4], l_i[4];
#pragma unroll
    for (int r = 0; r < 4; ++r) { m_i[r] = -1e30f; l_i[r] = 0.f; }

    const int jt_lo = (i0 - WIN + 1) > 0 ? ((i0 - WIN + 1) >> 6) : 0;
    for (int jt = jt_lo; jt <= qt; ++jt) {
        const int j0 = jt * 64;
#pragma unroll
        for (int it = 0; it < 2; ++it) {
            const int j = it * 32 + (tid >> 3);
            const int dh0 = (tid & 7) * 8;
            u16x8 vv = *(const u16x8*)(Vg + ((size_t)(b * S + j0 + j)) * 512 + hkv * 64 + dh0);
#pragma unroll
            for (int e = 0; e < 8; ++e) Vt[(dh0 + e) * 72 + j] = vv[e];
        }
        f32x4 sacc[4];
#pragma unroll
        for (int ni = 0; ni < 4; ++ni) sacc[ni] = {0.f, 0.f, 0.f, 0.f};
#pragma unroll
        for (int kk = 0; kk < 2; ++kk) {
#pragma unroll
            for (int ni = 0; ni < 4; ++ni) {
                bf16x8 bkf = *(const bf16x8*)(Kg + ((size_t)(b * S + j0 + ni * 16 + l15)) * 512 +
                                              hkv * 64 + kk * 32 + quad * 8);
                sacc[ni] = MFMA_BF16(aq[kk], bkf, sacc[ni]);
            }
        }
#pragma unroll
        for (int r = 0; r < 4; ++r) {
            const int i = i0 + wave * 16 + quad * 4 + r;
            float sv[4];
            float rowmax = -1e30f;
#pragma unroll
            for (int ni = 0; ni < 4; ++ni) {
                const int j = j0 + ni * 16 + l15;
                float s = sacc[ni][r] * SCALE + slope * (float)(j - i);
                const bool valid = (j <= i) && ((i - j) < WIN);
                s = valid ? s : -1e30f;
                sv[ni] = s;
                rowmax = fmaxf(rowmax, s);
            }
#pragma unroll
            for (int off = 1; off < 16; off <<= 1)
                rowmax = fmaxf(rowmax, __shfl_xor(rowmax, off));
            const float mn = fmaxf(m_i[r], rowmax);
            const float alpha = exp2f((m_i[r] - mn) * LOG2E);
            float rowsum = 0.f;
#pragma unroll
            for (int ni = 0; ni < 4; ++ni) {
                const float p = (sv[ni] > -1e29f) ? exp2f((sv[ni] - mn) * LOG2E) : 0.f;
                P_lds[(wave * 16 + quad * 4 + r) * 72 + ni * 16 + l15] = f2bfbits(p);
                rowsum += p;
            }
#pragma unroll
            for (int off = 1; off < 16; off <<= 1) rowsum += __shfl_xor(rowsum, off);
            l_i[r] = l_i[r] * alpha + rowsum;
            m_i[r] = mn;
#pragma unroll
            for (int ni = 0; ni < 4; ++ni) oacc[ni][r] *= alpha;
        }
        __syncthreads();
#pragma unroll
        for (int kk = 0; kk < 2; ++kk) {
            bf16x8 ap = *(const bf16x8*)(P_lds + (wave * 16 + l15) * 72 + kk * 32 + quad * 8);
#pragma unroll
            for (int ni = 0; ni < 4; ++ni) {
                bf16x8 bvf = *(const bf16x8*)(Vt + (ni * 16 + l15) * 72 + kk * 32 + quad * 8);
                oacc[ni] = MFMA_BF16(ap, bvf, oacc[ni]);
            }
        }
        __syncthreads();
    }
#pragma unroll
    for (int ni = 0; ni < 4; ++ni) {
#pragma unroll
        for (int r = 0; r < 4; ++r) {
            const int srow = i0 + wave * 16 + quad * 4 + r;
            const float v = oacc[ni][r] / l_i[r];
            Og[((size_t)(b * S + srow)) * 2048 + h * 64 + ni * 16 + l15] = __float2bfloat16(v);
        }
    }
}

extern "C" void kernel_launch(void* const* d_in, const int* in_sizes, int n_in,
                              void* d_out, int out_size, void* d_ws, size_t ws_size,
                              hipStream_t stream) {
    (void)in_sizes; (void)n_in; (void)out_size;
    const void* X  = d_in[0];
    const void* Wq = d_in[1];
    const void* bq = d_in[2];
    const void* Wk = d_in[3];
    const void* bk = d_in[4];
    const void* Wv = d_in[5];
    const void* bv = d_in[6];
    const void* Wo = d_in[7];
    const void* bo = d_in[8];
    const void* sl = d_in[9];
    float* outp = (float*)d_out;

    char* ws = (char*)d_ws;
    const size_t SZ_X  = (size_t)4096 * 2048 * 2;  // 16.78 MB
    const size_t SZ_WQ = (size_t)2048 * 2048 * 2;  //  8.39 MB
    const size_t SZ_WK = (size_t)512 * 2048 * 2;   //  2.10 MB
    const size_t SZ_Q  = SZ_X;
    const size_t SZ_K  = (size_t)4096 * 512 * 2;   //  4.19 MB
    const size_t FAST_NEED = SZ_X + SZ_WQ + 2 * SZ_WK + SZ_Q + 2 * SZ_K + 65536;

    if (ws_size >= FAST_NEED) {
        size_t o = 0;
        __hip_bfloat16* Xb  = (__hip_bfloat16*)(ws + o); o += SZ_X;   // aliased by Ab
        __hip_bfloat16* Wqb = (__hip_bfloat16*)(ws + o); o += SZ_WQ;  // aliased by Wob
        __hip_bfloat16* Wkb = (__hip_bfloat16*)(ws + o); o += SZ_WK;  // aliased by Vtg
        __hip_bfloat16* Wvb = (__hip_bfloat16*)(ws + o); o += SZ_WK;  //   (cont.)
        __hip_bfloat16* Qb  = (__hip_bfloat16*)(ws + o); o += SZ_Q;
        __hip_bfloat16* Kb  = (__hip_bfloat16*)(ws + o); o += SZ_K;
        __hip_bfloat16* Vb  = (__hip_bfloat16*)(ws + o); o += SZ_K;
        __hip_bfloat16* Ab  = Xb;             // X dead after qkv_fast
        __hip_bfloat16* Wob = Wqb;            // Wq dead after qkv_fast
        ushort_t*       Vtg = (ushort_t*)Wkb; // Wk/Wv dead after qkv_fast (4.19MB = SZ_K)
        int*   flag    = (int*)(ws + o);
        float* slopesF = (float*)(ws + o + 1024);
        float* bqF     = (float*)(ws + o + 4096);
        float* bkF     = bqF + 2048;
        float* bvF     = bkF + 512;
        float* boF     = bvF + 512;

        detect_kernel<<<1, 256, 0, stream>>>((const ushort_t*)X, bq, bk, bv, bo, sl,
                                             flag, slopesF, bqF, bkF, bvF, boF);
        cvt_kernel<<<2048, 256, 0, stream>>>(flag, X,  (ushort_t*)Xb,  4096 * 2048 / 4);
        cvt_kernel<<<2048, 256, 0, stream>>>(flag, Wq, (ushort_t*)Wqb, 2048 * 2048 / 4);
        cvt_kernel<<<512,  256, 0, stream>>>(flag, Wk, (ushort_t*)Wkb, 512 * 2048 / 4);
        cvt_kernel<<<512,  256, 0, stream>>>(flag, Wv, (ushort_t*)Wvb, 512 * 2048 / 4);
        qkv_fast<<<dim3(24, 32), 256, 0, stream>>>(Xb, Wqb, Wkb, Wvb, bqF, bkF, bvF,
                                                   Qb, Kb, Vb);
        vtrans_kernel<<<1024, 256, 0, stream>>>((const ushort_t*)Vb, Vtg);
        cvt_kernel<<<2048, 256, 0, stream>>>(flag, Wo, (ushort_t*)Wob, 2048 * 2048 / 4);
        attn2_kernel<<<dim3(2048), 256, 0, stream>>>(Qb, Kb, Vtg, slopesF, Ab);
        oproj_fast<<<dim3(16, 32), 256, 0, stream>>>(Ab, Wob, boF, outp);
    } else {
        const size_t MB = 1024 * 1024;
        __hip_bfloat16* Qb = (__hip_bfloat16*)(ws);
        __hip_bfloat16* Kb = (__hip_bfloat16*)(ws + 16 * MB);
        __hip_bfloat16* Vb = (__hip_bfloat16*)(ws + 20 * MB);
        __hip_bfloat16* Ab = (__hip_bfloat16*)(ws + 24 * MB);
        int*   flag    = (int*)(ws + 40 * MB);
        float* slopesF = (float*)(ws + 40 * MB + 1024);
        float* bqF     = (float*)(ws + 40 * MB + 4096);
        float* bkF     = bqF + 2048;
        float* bvF     = bkF + 512;
        float* boF     = bvF + 512;

        detect_kernel<<<1, 256, 0, stream>>>((const ushort_t*)X, bq, bk, bv, bo, sl,
                                             flag, slopesF, bqF, bkF, bvF, boF);
        qkv_kernel<false><<<dim3(24, 32), 256, 0, stream>>>(flag, X, Wq, Wk, Wv,
                                                            bqF, bkF, bvF, Qb, Kb, Vb);
        qkv_kernel<true><<<dim3(24, 32), 256, 0, stream>>>(flag, X, Wq, Wk, Wv,
                                                           bqF, bkF, bvF, Qb, Kb, Vb);
        attn_kernel<<<dim3(2048), 256, 0, stream>>>(Qb, Kb, Vb, slopesF, Ab);
        oproj_kernel<false><<<dim3(16, 32), 256, 0, stream>>>(flag, Ab, Wo, boF, outp);
        oproj_kernel<true><<<dim3(16, 32), 256, 0, stream>>>(flag, Ab, Wo, boF, outp);
    }
}

// Round 6
// 438.128 us; speedup vs baseline: 1.1413x; 1.1413x over previous
//
#include <hip/hip_runtime.h>
#include <hip/hip_bf16.h>
#include <stdint.h>
#include <type_traits>

typedef unsigned short ushort_t;
typedef __bf16 bf16x8 __attribute__((ext_vector_type(8)));
typedef unsigned short u16x8 __attribute__((ext_vector_type(8)));
typedef float f32x4 __attribute__((ext_vector_type(4)));

#define MFMA_BF16(a, b, c) __builtin_amdgcn_mfma_f32_16x16x32_bf16((a), (b), (c), 0, 0, 0)

#define GLD_LDS(gptr, lptr) \
    __builtin_amdgcn_global_load_lds((const __attribute__((address_space(1))) void*)(gptr), \
                                     (__attribute__((address_space(3))) void*)(lptr), 16, 0, 0)

static __device__ __forceinline__ float bf2f(__hip_bfloat16 x) { return __bfloat162float(x); }
static __device__ __forceinline__ ushort_t f2bfbits(float f) {
    __hip_bfloat16 h = __float2bfloat16(f);
    return *(ushort_t*)&h;
}

template <typename T>
static __device__ __forceinline__ void storeT(T* p, float v);
template <>
__device__ __forceinline__ void storeT<float>(float* p, float v) { *p = v; }
template <>
__device__ __forceinline__ void storeT<__hip_bfloat16>(__hip_bfloat16* p, float v) {
    *p = __float2bfloat16(v);
}

// ---------------------------------------------------------------------------
// dtype probe + bias/slope pre-convert.
// ---------------------------------------------------------------------------
__global__ void detect_kernel(const ushort_t* __restrict__ X,
                              const void* bq, const void* bk, const void* bv,
                              const void* bo, const void* slopes,
                              int* flag, float* slopesF, float* bqF,
                              float* bkF, float* bvF, float* boF) {
    __shared__ int cnt_s;
    if (threadIdx.x == 0) cnt_s = 0;
    __syncthreads();
    int cnt = 0;
    for (int i = threadIdx.x; i < 8192; i += 256) {
        ushort_t u = X[2 * i];
        int ex = (u >> 7) & 0xFF;
        if (ex >= 0xC0) cnt++;
    }
    for (int off = 1; off < 64; off <<= 1) cnt += __shfl_xor(cnt, off);
    if ((threadIdx.x & 63) == 0) atomicAdd(&cnt_s, cnt);
    __syncthreads();
    const bool f32 = cnt_s > 100;
    if (threadIdx.x == 0) *flag = f32 ? 1 : 0;
    auto conv = [&](const void* src, float* dst, int n) {
        for (int i = threadIdx.x; i < n; i += 256)
            dst[i] = f32 ? ((const float*)src)[i]
                         : __bfloat162float(((const __hip_bfloat16*)src)[i]);
    };
    conv(bq, bqF, 2048);
    conv(bk, bkF, 512);
    conv(bv, bvF, 512);
    conv(bo, boF, 2048);
    conv(slopes, slopesF, 32);
}

// ---------------------------------------------------------------------------
// Bulk dtype convert (fp32->bf16 or bf16 copy).
// ---------------------------------------------------------------------------
__global__ __launch_bounds__(256) void cvt_kernel(const int* __restrict__ flag,
                                                  const void* __restrict__ src,
                                                  ushort_t* __restrict__ dst, int n4) {
    const bool f32 = (*flag == 1);
    const int stride = gridDim.x * 256;
    for (int i = blockIdx.x * 256 + threadIdx.x; i < n4; i += stride) {
        if (f32) {
            float4 f = ((const float4*)src)[i];
            ((ushort4*)dst)[i] =
                make_ushort4(f2bfbits(f.x), f2bfbits(f.y), f2bfbits(f.z), f2bfbits(f.w));
        } else {
            ((ushort4*)dst)[i] = ((const ushort4*)src)[i];
        }
    }
}

// ---------------------------------------------------------------------------
// GEMM tile staging into bf16 LDS [128][64] with XOR column-chunk swizzle.
// ---------------------------------------------------------------------------
__device__ __forceinline__ void stage_tile(const __hip_bfloat16* __restrict__ M, int K,
                                           int k0, ushort_t* lds, int tid) {
    const int wave = tid >> 6, lane = tid & 63;
    const int srow = lane >> 3;
    const int scol = ((lane & 7) ^ srow) * 8;
#pragma unroll
    for (int t = 0; t < 4; ++t) {
        const int chunk = wave * 4 + t;
        GLD_LDS((const ushort_t*)M + (size_t)(chunk * 8 + srow) * K + k0 + scol,
                lds + chunk * 512);
    }
}

__device__ __forceinline__ void stage_tile(const float* __restrict__ M, int K,
                                           int k0, ushort_t* lds, int tid) {
#pragma unroll
    for (int q = 0; q < 8; ++q) {
        const int idx = q * 256 + tid;
        const int row = idx >> 4;
        const int c4 = (idx & 15) * 4;
        float4 f = *(const float4*)(M + (size_t)row * K + k0 + c4);
        const int dcol = (((c4 >> 3) ^ (row & 7)) * 8) + (c4 & 7);
        *(ushort4*)(lds + row * 64 + dcol) =
            make_ushort4(f2bfbits(f.x), f2bfbits(f.y), f2bfbits(f.z), f2bfbits(f.w));
    }
}

// ---------------------------------------------------------------------------
// 128x128xK GEMM tile (swizzled LDS reads).
// ---------------------------------------------------------------------------
template <typename TA, typename TW, typename TC>
__device__ __forceinline__ void gemm_tile(const TA* __restrict__ A,
                                          const TW* __restrict__ W,
                                          const float* __restrict__ biasF,
                                          TC* __restrict__ C, int K, int ldc) {
    __shared__ __align__(16) ushort_t As[128 * 64];
    __shared__ __align__(16) ushort_t Bs[128 * 64];
    const int tid = threadIdx.x;
    const int wave = tid >> 6, lane = tid & 63;
    const int quad = lane >> 4, l15 = lane & 15;
    const int wm = (wave >> 1) * 64, wn = (wave & 1) * 64;
    const int sw = l15 & 7;

    f32x4 acc[4][4];
#pragma unroll
    for (int i = 0; i < 4; ++i)
#pragma unroll
        for (int j = 0; j < 4; ++j) acc[i][j] = {0.f, 0.f, 0.f, 0.f};

    for (int k0 = 0; k0 < K; k0 += 64) {
        stage_tile(A, K, k0, As, tid);
        stage_tile(W, K, k0, Bs, tid);
        __syncthreads();
#pragma unroll
        for (int kk = 0; kk < 2; ++kk) {
            const int chs = ((kk * 4 + quad) ^ sw) * 8;
            bf16x8 af[4], bfr[4];
#pragma unroll
            for (int mi = 0; mi < 4; ++mi)
                af[mi] = *(const bf16x8*)(As + (wm + mi * 16 + l15) * 64 + chs);
#pragma unroll
            for (int ni = 0; ni < 4; ++ni)
                bfr[ni] = *(const bf16x8*)(Bs + (wn + ni * 16 + l15) * 64 + chs);
#pragma unroll
            for (int mi = 0; mi < 4; ++mi)
#pragma unroll
                for (int ni = 0; ni < 4; ++ni)
                    acc[mi][ni] = MFMA_BF16(af[mi], bfr[ni], acc[mi][ni]);
        }
        __syncthreads();
    }
#pragma unroll
    for (int mi = 0; mi < 4; ++mi) {
#pragma unroll
        for (int ni = 0; ni < 4; ++ni) {
            const int col = wn + ni * 16 + l15;
            const float bv = biasF[col];
#pragma unroll
            for (int r = 0; r < 4; ++r) {
                const int row = wm + mi * 16 + quad * 4 + r;
                storeT(C + (size_t)row * ldc + col, acc[mi][ni][r] + bv);
            }
        }
    }
}

// ======================== FAST PATH (pure-bf16 GEMMs) =======================
__global__ __launch_bounds__(256, 2) void qkv_fast(
    const __hip_bfloat16* __restrict__ X,
    const __hip_bfloat16* __restrict__ Wq, const __hip_bfloat16* __restrict__ Wk,
    const __hip_bfloat16* __restrict__ Wv, const float* __restrict__ bqF,
    const float* __restrict__ bkF, const float* __restrict__ bvF,
    __hip_bfloat16* __restrict__ Qb, __hip_bfloat16* __restrict__ Kb,
    __hip_bfloat16* __restrict__ Vb) {
    const int nt = blockIdx.x, mt = blockIdx.y;
    const __hip_bfloat16* W;
    const float* bias;
    __hip_bfloat16* C;
    int ldc, colbase;
    if (nt < 16)      { W = Wq; bias = bqF; C = Qb; ldc = 2048; colbase = nt * 128; }
    else if (nt < 20) { W = Wk; bias = bkF; C = Kb; ldc = 512;  colbase = (nt - 16) * 128; }
    else              { W = Wv; bias = bvF; C = Vb; ldc = 512;  colbase = (nt - 20) * 128; }
    gemm_tile(X + (size_t)mt * 128 * 2048, W + (size_t)colbase * 2048, bias + colbase,
              C + (size_t)mt * 128 * ldc + colbase, 2048, ldc);
}

__global__ __launch_bounds__(256, 2) void oproj_fast(
    const __hip_bfloat16* __restrict__ A, const __hip_bfloat16* __restrict__ Wo,
    const float* __restrict__ boF, float* __restrict__ C) {
    gemm_tile(A + (size_t)blockIdx.y * 128 * 2048,
              Wo + (size_t)blockIdx.x * 128 * 2048, boF + blockIdx.x * 128,
              C + (size_t)blockIdx.y * 128 * 2048 + blockIdx.x * 128, 2048, 2048);
}

// ---------------------------------------------------------------------------
// V transpose: Vb[b*2048+s][hkv*64+dh] -> Vt[(b*8+hkv)*64+dh][s] (bf16).
// ---------------------------------------------------------------------------
__global__ __launch_bounds__(256) void vtrans_kernel(const ushort_t* __restrict__ Vb,
                                                     ushort_t* __restrict__ Vt) {
    const int blk = blockIdx.x;
    const int bh = blk >> 6;
    const int sc = blk & 63;
    const int tid = threadIdx.x;
    const int dh = tid & 63;
    const int s0 = sc * 32 + (tid >> 6) * 8;
    const int b = bh >> 3, hkv = bh & 7;
    u16x8 vv;
#pragma unroll
    for (int e = 0; e < 8; ++e)
        vv[e] = Vb[((size_t)(b * 2048 + s0 + e)) * 512 + hkv * 64 + dh];
    *(u16x8*)(Vt + ((size_t)(bh * 64 + dh)) * 2048 + s0) = vv;
}

// ==================== FALLBACK PATH GEMMs (round-3 style) ===================
template <bool F32>
__global__ __launch_bounds__(256, 2) void qkv_kernel(
    const int* __restrict__ flag, const void* __restrict__ Xv,
    const void* __restrict__ Wqv, const void* __restrict__ Wkv,
    const void* __restrict__ Wvv, const float* __restrict__ bqF,
    const float* __restrict__ bkF, const float* __restrict__ bvF,
    __hip_bfloat16* __restrict__ Qb, __hip_bfloat16* __restrict__ Kb,
    __hip_bfloat16* __restrict__ Vb) {
    if ((*flag == 1) != F32) return;
    using T = typename std::conditional<F32, float, __hip_bfloat16>::type;
    const T* X = (const T*)Xv;
    const int nt = blockIdx.x, mt = blockIdx.y;
    const T* W;
    const float* bias;
    __hip_bfloat16* C;
    int ldc, colbase;
    if (nt < 16)      { W = (const T*)Wqv; bias = bqF; C = Qb; ldc = 2048; colbase = nt * 128; }
    else if (nt < 20) { W = (const T*)Wkv; bias = bkF; C = Kb; ldc = 512;  colbase = (nt - 16) * 128; }
    else              { W = (const T*)Wvv; bias = bvF; C = Vb; ldc = 512;  colbase = (nt - 20) * 128; }
    gemm_tile(X + (size_t)mt * 128 * 2048, W + (size_t)colbase * 2048, bias + colbase,
              C + (size_t)mt * 128 * ldc + colbase, 2048, ldc);
}

template <bool F32>
__global__ __launch_bounds__(256, 2) void oproj_kernel(
    const int* __restrict__ flag, const __hip_bfloat16* __restrict__ A,
    const void* __restrict__ Wov, const float* __restrict__ boF,
    float* __restrict__ C) {
    if ((*flag == 1) != F32) return;
    using T = typename std::conditional<F32, float, __hip_bfloat16>::type;
    gemm_tile(A + (size_t)blockIdx.y * 128 * 2048,
              (const T*)Wov + (size_t)blockIdx.x * 128 * 2048, boF + blockIdx.x * 128,
              C + (size_t)blockIdx.y * 128 * 2048 + blockIdx.x * 128, 2048, 2048);
}

// ---------------------------------------------------------------------------
// Flash attention v3: K and V^T tiles staged into LDS via async
// global_load_lds (coalesced 8-rows/instr, XOR-swizzled slots), double-
// buffered across j-tiles with ONE barrier per tile; prefetch of tile jt+1
// issued right after the barrier overlaps compute of jt. P per-wave private.
// Separate __shared__ arrays per buffer so the compiler can prove
// ds_read(buf A) independent of global_load_lds(buf B).
// ---------------------------------------------------------------------------
__global__ __launch_bounds__(256, 4) void attn3_kernel(
    const __hip_bfloat16* __restrict__ Qg, const __hip_bfloat16* __restrict__ Kg,
    const ushort_t* __restrict__ Vt, const float* __restrict__ slopesF,
    __hip_bfloat16* __restrict__ Og) {
    constexpr int S = 2048, WIN = 1024;
    constexpr float LOG2E = 1.44269504f;
    constexpr float SCALE2 = 0.125f * LOG2E;
    constexpr float NEGBIG = -3e38f;
    __shared__ __align__(16) ushort_t K0s[64 * 64];
    __shared__ __align__(16) ushort_t V0s[64 * 64];
    __shared__ __align__(16) ushort_t K1s[64 * 64];
    __shared__ __align__(16) ushort_t V1s[64 * 64];
    __shared__ __align__(16) ushort_t P_lds[4 * 16 * 64];

    const int tile = blockIdx.x;
    const int qt = tile & 31;
    const int h = (tile >> 5) & 31;
    const int b = tile >> 10;
    const int i0 = qt * 64;
    const int hkv = h >> 2;
    const int bh = b * 8 + hkv;
    const int tid = threadIdx.x;
    const int wave = tid >> 6, lane = tid & 63;
    const int quad = lane >> 4, l15 = lane & 15;
    const int sw = l15 & 7;
    const int jl = lane >> 3, cc = lane & 7;
    const float slope2 = slopesF[h] * LOG2E;
    ushort_t* Pw = P_lds + wave * 1024;

    const ushort_t* kbase = (const ushort_t*)Kg + (size_t)(b * S) * 512 + hkv * 64;
    const ushort_t* vbase = Vt + ((size_t)bh * 64) * 2048;

    // stage 64x64 K-tile (rows=j) and V^T-tile (rows=dh) into LDS, swizzled.
    // wave stages rows wave*16 .. wave*16+15 of each; lane covers (row, chunk).
    auto stage = [&](int j0, ushort_t* Ks, ushort_t* Vs) {
        const int row0 = wave * 16;
#pragma unroll
        for (int t = 0; t < 2; ++t) {
            const int r = row0 + t * 8 + jl;
            GLD_LDS(kbase + (size_t)(j0 + r) * 512 + ((cc ^ (r & 7)) * 8),
                    Ks + (row0 + t * 8) * 64);
            GLD_LDS(vbase + (size_t)r * 2048 + j0 + ((cc ^ (r & 7)) * 8),
                    Vs + (row0 + t * 8) * 64);
        }
    };

    // Q fragments (A-layout) for this wave's 16 rows — one-time global read
    const int qrow = i0 + wave * 16 + l15;
    const __hip_bfloat16* qbase = Qg + ((size_t)(b * S + qrow)) * 2048 + h * 64;
    bf16x8 aq0 = *(const bf16x8*)(qbase + quad * 8);
    bf16x8 aq1 = *(const bf16x8*)(qbase + 32 + quad * 8);

    f32x4 oacc[4];
#pragma unroll
    for (int ni = 0; ni < 4; ++ni) oacc[ni] = {0.f, 0.f, 0.f, 0.f};
    float m_i[4], l_i[4];
#pragma unroll
    for (int r = 0; r < 4; ++r) { m_i[r] = -1e30f; l_i[r] = 0.f; }
    const int iw = i0 + wave * 16 + quad * 4;

    auto compute = [&](int j0, const ushort_t* Ks, const ushort_t* Vs) {
        // ---- S = Q K^T ----
        f32x4 sacc[4];
#pragma unroll
        for (int ni = 0; ni < 4; ++ni) sacc[ni] = {0.f, 0.f, 0.f, 0.f};
#pragma unroll
        for (int kk = 0; kk < 2; ++kk) {
            const int chs = ((kk * 4 + quad) ^ sw) * 8;
#pragma unroll
            for (int ni = 0; ni < 4; ++ni) {
                bf16x8 bkf = *(const bf16x8*)(Ks + (ni * 16 + l15) * 64 + chs);
                sacc[ni] = MFMA_BF16(kk ? aq1 : aq0, bkf, sacc[ni]);
            }
        }
        // ---- online softmax (log2 domain) ----
#pragma unroll
        for (int r = 0; r < 4; ++r) {
            const int i = iw + r;
            float sv[4];
#pragma unroll
            for (int ni = 0; ni < 4; ++ni) {
                const int rel = (j0 + ni * 16 + l15) - i;
                float s = fmaf(sacc[ni][r], SCALE2, slope2 * (float)rel);
                sv[ni] = ((unsigned)(-rel) < (unsigned)WIN) ? s : NEGBIG;
            }
            float rowmax = fmaxf(fmaxf(sv[0], sv[1]), fmaxf(sv[2], sv[3]));
#pragma unroll
            for (int off = 1; off < 16; off <<= 1)
                rowmax = fmaxf(rowmax, __shfl_xor(rowmax, off));
            const float mn = fmaxf(m_i[r], rowmax);
            const float alpha = exp2f(m_i[r] - mn);
            m_i[r] = mn;
            float p0 = exp2f(sv[0] - mn), p1 = exp2f(sv[1] - mn);
            float p2 = exp2f(sv[2] - mn), p3 = exp2f(sv[3] - mn);
            const int rl = quad * 4 + r;
            const int base = rl * 64 + (l15 & 7);
            const int swr = rl & 7;
            Pw[base + (((0 * 2 + (l15 >> 3)) ^ swr) * 8)] = f2bfbits(p0);
            Pw[base + (((1 * 2 + (l15 >> 3)) ^ swr) * 8)] = f2bfbits(p1);
            Pw[base + (((2 * 2 + (l15 >> 3)) ^ swr) * 8)] = f2bfbits(p2);
            Pw[base + (((3 * 2 + (l15 >> 3)) ^ swr) * 8)] = f2bfbits(p3);
            float rowsum = (p0 + p1) + (p2 + p3);
#pragma unroll
            for (int off = 1; off < 16; off <<= 1) rowsum += __shfl_xor(rowsum, off);
            l_i[r] = l_i[r] * alpha + rowsum;
#pragma unroll
            for (int ni = 0; ni < 4; ++ni) oacc[ni][r] *= alpha;
        }
        // ---- O += P @ V ----
#pragma unroll
        for (int kk = 0; kk < 2; ++kk) {
            const int chs = ((kk * 4 + quad) ^ sw) * 8;
            bf16x8 ap = *(const bf16x8*)(Pw + l15 * 64 + chs);
#pragma unroll
            for (int ni = 0; ni < 4; ++ni) {
                bf16x8 bvf = *(const bf16x8*)(Vs + (ni * 16 + l15) * 64 + chs);
                oacc[ni] = MFMA_BF16(ap, bvf, oacc[ni]);
            }
        }
    };

    const int jt_lo = (i0 - WIN + 1) > 0 ? ((i0 - WIN + 1) >> 6) : 0;
    int jt = jt_lo;
    stage(jt * 64, K0s, V0s);
    for (;;) {
        __syncthreads();  // buf0 staging complete (drains this wave's vmcnt)
        if (jt < qt) stage((jt + 1) * 64, K1s, V1s);  // prefetch into buf1
        compute(jt * 64, K0s, V0s);
        if (++jt > qt) break;
        __syncthreads();  // buf1 staging complete
        if (jt < qt) stage((jt + 1) * 64, K0s, V0s);  // prefetch into buf0
        compute(jt * 64, K1s, V1s);
        if (++jt > qt) break;
    }
    // epilogue
#pragma unroll
    for (int ni = 0; ni < 4; ++ni) {
#pragma unroll
        for (int r = 0; r < 4; ++r) {
            const int srow = iw + r;
            const float v = oacc[ni][r] / l_i[r];
            Og[((size_t)(b * S + srow)) * 2048 + h * 64 + ni * 16 + l15] = __float2bfloat16(v);
        }
    }
}

// ---------------------------------------------------------------------------
// Fallback attention (round-3 proven; used when ws too small for fast path).
// ---------------------------------------------------------------------------
__global__ __launch_bounds__(256, 2) void attn_kernel(
    const __hip_bfloat16* __restrict__ Qg, const __hip_bfloat16* __restrict__ Kg,
    const __hip_bfloat16* __restrict__ Vg, const float* __restrict__ slopesF,
    __hip_bfloat16* __restrict__ Og) {
    constexpr int S = 2048, WIN = 1024;
    constexpr float SCALE = 0.125f;
    constexpr float LOG2E = 1.44269504f;
    __shared__ __align__(16) ushort_t P_lds[64 * 72];
    __shared__ __align__(16) ushort_t Vts[64 * 72];

    const int tile = blockIdx.x;
    const int qt = tile & 31;
    const int h = (tile >> 5) & 31;
    const int b = tile >> 10;
    const int i0 = qt * 64;
    const int hkv = h >> 2;
    const int tid = threadIdx.x;
    const int wave = tid >> 6, lane = tid & 63;
    const int quad = lane >> 4, l15 = lane & 15;
    const float slope = slopesF[h];

    const int qrow = i0 + wave * 16 + l15;
    const __hip_bfloat16* qbase = Qg + ((size_t)(b * S + qrow)) * 2048 + h * 64;
    bf16x8 aq[2];
    aq[0] = *(const bf16x8*)(qbase + quad * 8);
    aq[1] = *(const bf16x8*)(qbase + 32 + quad * 8);

    f32x4 oacc[4];
#pragma unroll
    for (int ni = 0; ni < 4; ++ni) oacc[ni] = {0.f, 0.f, 0.f, 0.f};
    float m_i[4], l_i[4];
#pragma unroll
    for (int r = 0; r < 4; ++r) { m_i[r] = -1e30f; l_i[r] = 0.f; }

    const int jt_lo = (i0 - WIN + 1) > 0 ? ((i0 - WIN + 1) >> 6) : 0;
    for (int jt = jt_lo; jt <= qt; ++jt) {
        const int j0 = jt * 64;
#pragma unroll
        for (int it = 0; it < 2; ++it) {
            const int j = it * 32 + (tid >> 3);
            const int dh0 = (tid & 7) * 8;
            u16x8 vv = *(const u16x8*)(Vg + ((size_t)(b * S + j0 + j)) * 512 + hkv * 64 + dh0);
#pragma unroll
            for (int e = 0; e < 8; ++e) Vts[(dh0 + e) * 72 + j] = vv[e];
        }
        f32x4 sacc[4];
#pragma unroll
        for (int ni = 0; ni < 4; ++ni) sacc[ni] = {0.f, 0.f, 0.f, 0.f};
#pragma unroll
        for (int kk = 0; kk < 2; ++kk) {
#pragma unroll
            for (int ni = 0; ni < 4; ++ni) {
                bf16x8 bkf = *(const bf16x8*)(Kg + ((size_t)(b * S + j0 + ni * 16 + l15)) * 512 +
                                              hkv * 64 + kk * 32 + quad * 8);
                sacc[ni] = MFMA_BF16(aq[kk], bkf, sacc[ni]);
            }
        }
#pragma unroll
        for (int r = 0; r < 4; ++r) {
            const int i = i0 + wave * 16 + quad * 4 + r;
            float sv[4];
            float rowmax = -1e30f;
#pragma unroll
            for (int ni = 0; ni < 4; ++ni) {
                const int j = j0 + ni * 16 + l15;
                float s = sacc[ni][r] * SCALE + slope * (float)(j - i);
                const bool valid = (j <= i) && ((i - j) < WIN);
                s = valid ? s : -1e30f;
                sv[ni] = s;
                rowmax = fmaxf(rowmax, s);
            }
#pragma unroll
            for (int off = 1; off < 16; off <<= 1)
                rowmax = fmaxf(rowmax, __shfl_xor(rowmax, off));
            const float mn = fmaxf(m_i[r], rowmax);
            const float alpha = exp2f((m_i[r] - mn) * LOG2E);
            float rowsum = 0.f;
#pragma unroll
            for (int ni = 0; ni < 4; ++ni) {
                const float p = (sv[ni] > -1e29f) ? exp2f((sv[ni] - mn) * LOG2E) : 0.f;
                P_lds[(wave * 16 + quad * 4 + r) * 72 + ni * 16 + l15] = f2bfbits(p);
                rowsum += p;
            }
#pragma unroll
            for (int off = 1; off < 16; off <<= 1) rowsum += __shfl_xor(rowsum, off);
            l_i[r] = l_i[r] * alpha + rowsum;
            m_i[r] = mn;
#pragma unroll
            for (int ni = 0; ni < 4; ++ni) oacc[ni][r] *= alpha;
        }
        __syncthreads();
#pragma unroll
        for (int kk = 0; kk < 2; ++kk) {
            bf16x8 ap = *(const bf16x8*)(P_lds + (wave * 16 + l15) * 72 + kk * 32 + quad * 8);
#pragma unroll
            for (int ni = 0; ni < 4; ++ni) {
                bf16x8 bvf = *(const bf16x8*)(Vts + (ni * 16 + l15) * 72 + kk * 32 + quad * 8);
                oacc[ni] = MFMA_BF16(ap, bvf, oacc[ni]);
            }
        }
        __syncthreads();
    }
#pragma unroll
    for (int ni = 0; ni < 4; ++ni) {
#pragma unroll
        for (int r = 0; r < 4; ++r) {
            const int srow = i0 + wave * 16 + quad * 4 + r;
            const float v = oacc[ni][r] / l_i[r];
            Og[((size_t)(b * S + srow)) * 2048 + h * 64 + ni * 16 + l15] = __float2bfloat16(v);
        }
    }
}

extern "C" void kernel_launch(void* const* d_in, const int* in_sizes, int n_in,
                              void* d_out, int out_size, void* d_ws, size_t ws_size,
                              hipStream_t stream) {
    (void)in_sizes; (void)n_in; (void)out_size;
    const void* X  = d_in[0];
    const void* Wq = d_in[1];
    const void* bq = d_in[2];
    const void* Wk = d_in[3];
    const void* bk = d_in[4];
    const void* Wv = d_in[5];
    const void* bv = d_in[6];
    const void* Wo = d_in[7];
    const void* bo = d_in[8];
    const void* sl = d_in[9];
    float* outp = (float*)d_out;

    char* ws = (char*)d_ws;
    const size_t SZ_X  = (size_t)4096 * 2048 * 2;
    const size_t SZ_WQ = (size_t)2048 * 2048 * 2;
    const size_t SZ_WK = (size_t)512 * 2048 * 2;
    const size_t SZ_Q  = SZ_X;
    const size_t SZ_K  = (size_t)4096 * 512 * 2;
    const size_t FAST_NEED = SZ_X + SZ_WQ + 2 * SZ_WK + SZ_Q + 2 * SZ_K + 65536;

    if (ws_size >= FAST_NEED) {
        size_t o = 0;
        __hip_bfloat16* Xb  = (__hip_bfloat16*)(ws + o); o += SZ_X;
        __hip_bfloat16* Wqb = (__hip_bfloat16*)(ws + o); o += SZ_WQ;
        __hip_bfloat16* Wkb = (__hip_bfloat16*)(ws + o); o += SZ_WK;
        __hip_bfloat16* Wvb = (__hip_bfloat16*)(ws + o); o += SZ_WK;
        __hip_bfloat16* Qb  = (__hip_bfloat16*)(ws + o); o += SZ_Q;
        __hip_bfloat16* Kb  = (__hip_bfloat16*)(ws + o); o += SZ_K;
        __hip_bfloat16* Vb  = (__hip_bfloat16*)(ws + o); o += SZ_K;
        __hip_bfloat16* Ab  = Xb;             // X dead after qkv_fast
        __hip_bfloat16* Wob = Wqb;            // Wq dead after qkv_fast
        ushort_t*       Vtg = (ushort_t*)Wkb; // Wk/Wv dead after qkv_fast
        int*   flag    = (int*)(ws + o);
        float* slopesF = (float*)(ws + o + 1024);
        float* bqF     = (float*)(ws + o + 4096);
        float* bkF     = bqF + 2048;
        float* bvF     = bkF + 512;
        float* boF     = bvF + 512;

        detect_kernel<<<1, 256, 0, stream>>>((const ushort_t*)X, bq, bk, bv, bo, sl,
                                             flag, slopesF, bqF, bkF, bvF, boF);
        cvt_kernel<<<2048, 256, 0, stream>>>(flag, X,  (ushort_t*)Xb,  4096 * 2048 / 4);
        cvt_kernel<<<2048, 256, 0, stream>>>(flag, Wq, (ushort_t*)Wqb, 2048 * 2048 / 4);
        cvt_kernel<<<512,  256, 0, stream>>>(flag, Wk, (ushort_t*)Wkb, 512 * 2048 / 4);
        cvt_kernel<<<512,  256, 0, stream>>>(flag, Wv, (ushort_t*)Wvb, 512 * 2048 / 4);
        qkv_fast<<<dim3(24, 32), 256, 0, stream>>>(Xb, Wqb, Wkb, Wvb, bqF, bkF, bvF,
                                                   Qb, Kb, Vb);
        vtrans_kernel<<<1024, 256, 0, stream>>>((const ushort_t*)Vb, Vtg);
        cvt_kernel<<<2048, 256, 0, stream>>>(flag, Wo, (ushort_t*)Wob, 2048 * 2048 / 4);
        attn3_kernel<<<dim3(2048), 256, 0, stream>>>(Qb, Kb, Vtg, slopesF, Ab);
        oproj_fast<<<dim3(16, 32), 256, 0, stream>>>(Ab, Wob, boF, outp);
    } else {
        const size_t MB = 1024 * 1024;
        __hip_bfloat16* Qb = (__hip_bfloat16*)(ws);
        __hip_bfloat16* Kb = (__hip_bfloat16*)(ws + 16 * MB);
        __hip_bfloat16* Vb = (__hip_bfloat16*)(ws + 20 * MB);
        __hip_bfloat16* Ab = (__hip_bfloat16*)(ws + 24 * MB);
        int*   flag    = (int*)(ws + 40 * MB);
        float* slopesF = (float*)(ws + 40 * MB + 1024);
        float* bqF     = (float*)(ws + 40 * MB + 4096);
        float* bkF     = bqF + 2048;
        float* bvF     = bkF + 512;
        float* boF     = bvF + 512;

        detect_kernel<<<1, 256, 0, stream>>>((const ushort_t*)X, bq, bk, bv, bo, sl,
                                             flag, slopesF, bqF, bkF, bvF, boF);
        qkv_kernel<false><<<dim3(24, 32), 256, 0, stream>>>(flag, X, Wq, Wk, Wv,
                                                            bqF, bkF, bvF, Qb, Kb, Vb);
        qkv_kernel<true><<<dim3(24, 32), 256, 0, stream>>>(flag, X, Wq, Wk, Wv,
                                                           bqF, bkF, bvF, Qb, Kb, Vb);
        attn_kernel<<<dim3(2048), 256, 0, stream>>>(Qb, Kb, Vb, slopesF, Ab);
        oproj_kernel<false><<<dim3(16, 32), 256, 0, stream>>>(flag, Ab, Wo, boF, outp);
        oproj_kernel<true><<<dim3(16, 32), 256, 0, stream>>>(flag, Ab, Wo, boF, outp);
    }
}

// Round 7
// 338.310 us; speedup vs baseline: 1.4780x; 1.2950x over previous
//
#include <hip/hip_runtime.h>
#include <hip/hip_bf16.h>
#include <stdint.h>
#include <type_traits>

typedef unsigned short ushort_t;
typedef __bf16 bf16x8 __attribute__((ext_vector_type(8)));
typedef __bf16 bf16x4 __attribute__((ext_vector_type(4)));
typedef short s16x4 __attribute__((ext_vector_type(4)));
typedef unsigned short u16x8 __attribute__((ext_vector_type(8)));
typedef float f32x4 __attribute__((ext_vector_type(4)));

#define MFMA_BF16(a, b, c) __builtin_amdgcn_mfma_f32_16x16x32_bf16((a), (b), (c), 0, 0, 0)

#define GLD_LDS(gptr, lptr) \
    __builtin_amdgcn_global_load_lds((const __attribute__((address_space(1))) void*)(gptr), \
                                     (__attribute__((address_space(3))) void*)(lptr), 16, 0, 0)

static __device__ __forceinline__ float bf2f(__hip_bfloat16 x) { return __bfloat162float(x); }
static __device__ __forceinline__ ushort_t f2bfbits(float f) {
    __hip_bfloat16 h = __float2bfloat16(f);
    return *(ushort_t*)&h;
}

// 16x16x16 bf16 MFMA with graceful fallback (zero-padded K=32 is exact).
static __device__ __forceinline__ f32x4 MFMA16(bf16x4 a, bf16x4 b, f32x4 c) {
#if __has_builtin(__builtin_amdgcn_mfma_f32_16x16x16_bf16)
    return __builtin_amdgcn_mfma_f32_16x16x16_bf16(a, b, c, 0, 0, 0);
#elif __has_builtin(__builtin_amdgcn_mfma_f32_16x16x16bf16_1k)
    union { bf16x4 b4; s16x4 s4; } ua, ub;
    ua.b4 = a; ub.b4 = b;
    return __builtin_amdgcn_mfma_f32_16x16x16bf16_1k(ua.s4, ub.s4, c, 0, 0, 0);
#else
    const bf16x4 z = {(__bf16)0.f, (__bf16)0.f, (__bf16)0.f, (__bf16)0.f};
    bf16x8 a8 = __builtin_shufflevector(a, z, 0, 1, 2, 3, 4, 5, 6, 7);
    bf16x8 b8 = __builtin_shufflevector(b, z, 0, 1, 2, 3, 4, 5, 6, 7);
    return MFMA_BF16(a8, b8, c);
#endif
}

static __device__ __forceinline__ bf16x4 pack4(float a, float b, float c, float d) {
    union { ushort4 u; bf16x4 v; } r;
    r.u = make_ushort4(f2bfbits(a), f2bfbits(b), f2bfbits(c), f2bfbits(d));
    return r.v;
}

template <typename T>
static __device__ __forceinline__ void storeT(T* p, float v);
template <>
__device__ __forceinline__ void storeT<float>(float* p, float v) { *p = v; }
template <>
__device__ __forceinline__ void storeT<__hip_bfloat16>(__hip_bfloat16* p, float v) {
    *p = __float2bfloat16(v);
}

// ---------------------------------------------------------------------------
// dtype probe + bias/slope pre-convert.
// ---------------------------------------------------------------------------
__global__ void detect_kernel(const ushort_t* __restrict__ X,
                              const void* bq, const void* bk, const void* bv,
                              const void* bo, const void* slopes,
                              int* flag, float* slopesF, float* bqF,
                              float* bkF, float* bvF, float* boF) {
    __shared__ int cnt_s;
    if (threadIdx.x == 0) cnt_s = 0;
    __syncthreads();
    int cnt = 0;
    for (int i = threadIdx.x; i < 8192; i += 256) {
        ushort_t u = X[2 * i];
        int ex = (u >> 7) & 0xFF;
        if (ex >= 0xC0) cnt++;
    }
    for (int off = 1; off < 64; off <<= 1) cnt += __shfl_xor(cnt, off);
    if ((threadIdx.x & 63) == 0) atomicAdd(&cnt_s, cnt);
    __syncthreads();
    const bool f32 = cnt_s > 100;
    if (threadIdx.x == 0) *flag = f32 ? 1 : 0;
    auto conv = [&](const void* src, float* dst, int n) {
        for (int i = threadIdx.x; i < n; i += 256)
            dst[i] = f32 ? ((const float*)src)[i]
                         : __bfloat162float(((const __hip_bfloat16*)src)[i]);
    };
    conv(bq, bqF, 2048);
    conv(bk, bkF, 512);
    conv(bv, bvF, 512);
    conv(bo, boF, 2048);
    conv(slopes, slopesF, 32);
}

// ---------------------------------------------------------------------------
// Bulk dtype convert (fp32->bf16 or bf16 copy).
// ---------------------------------------------------------------------------
__global__ __launch_bounds__(256) void cvt_kernel(const int* __restrict__ flag,
                                                  const void* __restrict__ src,
                                                  ushort_t* __restrict__ dst, int n4) {
    const bool f32 = (*flag == 1);
    const int stride = gridDim.x * 256;
    for (int i = blockIdx.x * 256 + threadIdx.x; i < n4; i += stride) {
        if (f32) {
            float4 f = ((const float4*)src)[i];
            ((ushort4*)dst)[i] =
                make_ushort4(f2bfbits(f.x), f2bfbits(f.y), f2bfbits(f.z), f2bfbits(f.w));
        } else {
            ((ushort4*)dst)[i] = ((const ushort4*)src)[i];
        }
    }
}

// ---------------------------------------------------------------------------
// GEMM tile staging into bf16 LDS [128][64] with XOR column-chunk swizzle.
// ---------------------------------------------------------------------------
__device__ __forceinline__ void stage_tile(const __hip_bfloat16* __restrict__ M, int K,
                                           int k0, ushort_t* lds, int tid) {
    const int wave = tid >> 6, lane = tid & 63;
    const int srow = lane >> 3;
    const int scol = ((lane & 7) ^ srow) * 8;
#pragma unroll
    for (int t = 0; t < 4; ++t) {
        const int chunk = wave * 4 + t;
        GLD_LDS((const ushort_t*)M + (size_t)(chunk * 8 + srow) * K + k0 + scol,
                lds + chunk * 512);
    }
}

__device__ __forceinline__ void stage_tile(const float* __restrict__ M, int K,
                                           int k0, ushort_t* lds, int tid) {
#pragma unroll
    for (int q = 0; q < 8; ++q) {
        const int idx = q * 256 + tid;
        const int row = idx >> 4;
        const int c4 = (idx & 15) * 4;
        float4 f = *(const float4*)(M + (size_t)row * K + k0 + c4);
        const int dcol = (((c4 >> 3) ^ (row & 7)) * 8) + (c4 & 7);
        *(ushort4*)(lds + row * 64 + dcol) =
            make_ushort4(f2bfbits(f.x), f2bfbits(f.y), f2bfbits(f.z), f2bfbits(f.w));
    }
}

// ---------------------------------------------------------------------------
// 128x128xK GEMM tile (swizzled LDS reads).
// ---------------------------------------------------------------------------
template <typename TA, typename TW, typename TC>
__device__ __forceinline__ void gemm_tile(const TA* __restrict__ A,
                                          const TW* __restrict__ W,
                                          const float* __restrict__ biasF,
                                          TC* __restrict__ C, int K, int ldc) {
    __shared__ __align__(16) ushort_t As[128 * 64];
    __shared__ __align__(16) ushort_t Bs[128 * 64];
    const int tid = threadIdx.x;
    const int wave = tid >> 6, lane = tid & 63;
    const int quad = lane >> 4, l15 = lane & 15;
    const int wm = (wave >> 1) * 64, wn = (wave & 1) * 64;
    const int sw = l15 & 7;

    f32x4 acc[4][4];
#pragma unroll
    for (int i = 0; i < 4; ++i)
#pragma unroll
        for (int j = 0; j < 4; ++j) acc[i][j] = {0.f, 0.f, 0.f, 0.f};

    for (int k0 = 0; k0 < K; k0 += 64) {
        stage_tile(A, K, k0, As, tid);
        stage_tile(W, K, k0, Bs, tid);
        __syncthreads();
#pragma unroll
        for (int kk = 0; kk < 2; ++kk) {
            const int chs = ((kk * 4 + quad) ^ sw) * 8;
            bf16x8 af[4], bfr[4];
#pragma unroll
            for (int mi = 0; mi < 4; ++mi)
                af[mi] = *(const bf16x8*)(As + (wm + mi * 16 + l15) * 64 + chs);
#pragma unroll
            for (int ni = 0; ni < 4; ++ni)
                bfr[ni] = *(const bf16x8*)(Bs + (wn + ni * 16 + l15) * 64 + chs);
#pragma unroll
            for (int mi = 0; mi < 4; ++mi)
#pragma unroll
                for (int ni = 0; ni < 4; ++ni)
                    acc[mi][ni] = MFMA_BF16(af[mi], bfr[ni], acc[mi][ni]);
        }
        __syncthreads();
    }
#pragma unroll
    for (int mi = 0; mi < 4; ++mi) {
#pragma unroll
        for (int ni = 0; ni < 4; ++ni) {
            const int col = wn + ni * 16 + l15;
            const float bv = biasF[col];
#pragma unroll
            for (int r = 0; r < 4; ++r) {
                const int row = wm + mi * 16 + quad * 4 + r;
                storeT(C + (size_t)row * ldc + col, acc[mi][ni][r] + bv);
            }
        }
    }
}

// ======================== FAST PATH (pure-bf16 GEMMs) =======================
__global__ __launch_bounds__(256, 2) void qkv_fast(
    const __hip_bfloat16* __restrict__ X,
    const __hip_bfloat16* __restrict__ Wq, const __hip_bfloat16* __restrict__ Wk,
    const __hip_bfloat16* __restrict__ Wv, const float* __restrict__ bqF,
    const float* __restrict__ bkF, const float* __restrict__ bvF,
    __hip_bfloat16* __restrict__ Qb, __hip_bfloat16* __restrict__ Kb,
    __hip_bfloat16* __restrict__ Vb) {
    const int nt = blockIdx.x, mt = blockIdx.y;
    const __hip_bfloat16* W;
    const float* bias;
    __hip_bfloat16* C;
    int ldc, colbase;
    if (nt < 16)      { W = Wq; bias = bqF; C = Qb; ldc = 2048; colbase = nt * 128; }
    else if (nt < 20) { W = Wk; bias = bkF; C = Kb; ldc = 512;  colbase = (nt - 16) * 128; }
    else              { W = Wv; bias = bvF; C = Vb; ldc = 512;  colbase = (nt - 20) * 128; }
    gemm_tile(X + (size_t)mt * 128 * 2048, W + (size_t)colbase * 2048, bias + colbase,
              C + (size_t)mt * 128 * ldc + colbase, 2048, ldc);
}

__global__ __launch_bounds__(256, 2) void oproj_fast(
    const __hip_bfloat16* __restrict__ A, const __hip_bfloat16* __restrict__ Wo,
    const float* __restrict__ boF, float* __restrict__ C) {
    gemm_tile(A + (size_t)blockIdx.y * 128 * 2048,
              Wo + (size_t)blockIdx.x * 128 * 2048, boF + blockIdx.x * 128,
              C + (size_t)blockIdx.y * 128 * 2048 + blockIdx.x * 128, 2048, 2048);
}

// ---------------------------------------------------------------------------
// V transpose: Vb[b*2048+s][hkv*64+dh] -> Vt[(b*8+hkv)*64+dh][s] (bf16).
// ---------------------------------------------------------------------------
__global__ __launch_bounds__(256) void vtrans_kernel(const ushort_t* __restrict__ Vb,
                                                     ushort_t* __restrict__ Vt) {
    const int blk = blockIdx.x;
    const int bh = blk >> 6;
    const int sc = blk & 63;
    const int tid = threadIdx.x;
    const int dh = tid & 63;
    const int s0 = sc * 32 + (tid >> 6) * 8;
    const int b = bh >> 3, hkv = bh & 7;
    u16x8 vv;
#pragma unroll
    for (int e = 0; e < 8; ++e)
        vv[e] = Vb[((size_t)(b * 2048 + s0 + e)) * 512 + hkv * 64 + dh];
    *(u16x8*)(Vt + ((size_t)(bh * 64 + dh)) * 2048 + s0) = vv;
}

// ==================== FALLBACK PATH GEMMs (round-3 style) ===================
template <bool F32>
__global__ __launch_bounds__(256, 2) void qkv_kernel(
    const int* __restrict__ flag, const void* __restrict__ Xv,
    const void* __restrict__ Wqv, const void* __restrict__ Wkv,
    const void* __restrict__ Wvv, const float* __restrict__ bqF,
    const float* __restrict__ bkF, const float* __restrict__ bvF,
    __hip_bfloat16* __restrict__ Qb, __hip_bfloat16* __restrict__ Kb,
    __hip_bfloat16* __restrict__ Vb) {
    if ((*flag == 1) != F32) return;
    using T = typename std::conditional<F32, float, __hip_bfloat16>::type;
    const T* X = (const T*)Xv;
    const int nt = blockIdx.x, mt = blockIdx.y;
    const T* W;
    const float* bias;
    __hip_bfloat16* C;
    int ldc, colbase;
    if (nt < 16)      { W = (const T*)Wqv; bias = bqF; C = Qb; ldc = 2048; colbase = nt * 128; }
    else if (nt < 20) { W = (const T*)Wkv; bias = bkF; C = Kb; ldc = 512;  colbase = (nt - 16) * 128; }
    else              { W = (const T*)Wvv; bias = bvF; C = Vb; ldc = 512;  colbase = (nt - 20) * 128; }
    gemm_tile(X + (size_t)mt * 128 * 2048, W + (size_t)colbase * 2048, bias + colbase,
              C + (size_t)mt * 128 * ldc + colbase, 2048, ldc);
}

template <bool F32>
__global__ __launch_bounds__(256, 2) void oproj_kernel(
    const int* __restrict__ flag, const __hip_bfloat16* __restrict__ A,
    const void* __restrict__ Wov, const float* __restrict__ boF,
    float* __restrict__ C) {
    if ((*flag == 1) != F32) return;
    using T = typename std::conditional<F32, float, __hip_bfloat16>::type;
    gemm_tile(A + (size_t)blockIdx.y * 128 * 2048,
              (const T*)Wov + (size_t)blockIdx.x * 128 * 2048, boF + blockIdx.x * 128,
              C + (size_t)blockIdx.y * 128 * 2048 + blockIdx.x * 128, 2048, 2048);
}

// ---------------------------------------------------------------------------
// Flash attention v4: S^T formulation. S^T = K·Q^T puts q on the lane axis:
// softmax state is scalar-per-lane (2 shuffles per reduction instead of 8),
// and the S^T accumulator registers ARE the B-operand fragments for the PV
// 16x16x16 MFMA — P never touches LDS. O accumulates transposed (q=lane),
// so alpha rescale / final 1/l are scalar. K & V^T tiles double-buffered in
// LDS via async global_load_lds (swizzled, conflict-free). Interior tiles
// skip mask selects (uniform branch). XCD-aware block swizzle for K/V L2
// locality. LDS 32KB -> up to 5 blocks/CU.
// ---------------------------------------------------------------------------
__global__ __launch_bounds__(256, 4) void attn4_kernel(
    const __hip_bfloat16* __restrict__ Qg, const __hip_bfloat16* __restrict__ Kg,
    const ushort_t* __restrict__ Vt, const float* __restrict__ slopesF,
    __hip_bfloat16* __restrict__ Og) {
    constexpr int S = 2048, WIN = 1024;
    constexpr float LOG2E = 1.44269504f;
    constexpr float SCALE2 = 0.125f * LOG2E;
    constexpr float NEGBIG = -3e38f;
    __shared__ __align__(16) ushort_t K0s[64 * 64];
    __shared__ __align__(16) ushort_t V0s[64 * 64];
    __shared__ __align__(16) ushort_t K1s[64 * 64];
    __shared__ __align__(16) ushort_t V1s[64 * 64];

    // XCD-aware decode: blocks sharing (b,hkv) land on one XCD (p%8 = xcd).
    const int p = blockIdx.x;
    const int xcd = p & 7;
    const int slot = p >> 3;
    const int bh = (slot >> 7) * 8 + xcd;   // b*8 + hkv
    const int h2 = (slot >> 5) & 3;
    const int qt = slot & 31;
    const int b = bh >> 3, hkv = bh & 7;
    const int h = hkv * 4 + h2;
    const int i0 = qt * 64;

    const int tid = threadIdx.x;
    const int wave = tid >> 6, lane = tid & 63;
    const int quad = lane >> 4, l15 = lane & 15;
    const int jl = lane >> 3, cc = lane & 7;
    const float slope2 = slopesF[h] * LOG2E;

    const ushort_t* kbase = (const ushort_t*)Kg + (size_t)(b * S) * 512 + hkv * 64;
    const ushort_t* vbase = Vt + ((size_t)bh * 64) * 2048;

    auto stage = [&](int j0, ushort_t* Ks, ushort_t* Vs) {
        const int row0 = wave * 16;
#pragma unroll
        for (int t = 0; t < 2; ++t) {
            const int r = row0 + t * 8 + jl;
            GLD_LDS(kbase + (size_t)(j0 + r) * 512 + ((cc ^ (r & 7)) * 8),
                    Ks + (row0 + t * 8) * 64);
            GLD_LDS(vbase + (size_t)r * 2048 + j0 + ((cc ^ (r & 7)) * 8),
                    Vs + (row0 + t * 8) * 64);
        }
    };

    // Q fragments: lane holds Q[row=i][dh=kk*32+quad*8+..] -> B-operand of K·Q^T
    const int i = i0 + wave * 16 + l15;  // this lane's q-row
    const __hip_bfloat16* qbase = Qg + ((size_t)(b * S + i)) * 2048 + h * 64;
    bf16x8 aq0 = *(const bf16x8*)(qbase + quad * 8);
    bf16x8 aq1 = *(const bf16x8*)(qbase + 32 + quad * 8);

    f32x4 oaccT[4];  // O^T: lane holds q=i, dh = ni*16 + quad*4 + r
#pragma unroll
    for (int ni = 0; ni < 4; ++ni) oaccT[ni] = {0.f, 0.f, 0.f, 0.f};
    float m_i = -1e30f, l_i = 0.f;

    auto compute = [&](int j0, const ushort_t* Ks, const ushort_t* Vs, bool masked) {
        // ---- S^T = K·Q^T : D[j=ni*16+quad*4+r][q=l15] ----
        f32x4 st[4];
#pragma unroll
        for (int ni = 0; ni < 4; ++ni) st[ni] = {0.f, 0.f, 0.f, 0.f};
#pragma unroll
        for (int kk = 0; kk < 2; ++kk) {
            const bf16x8 aqk = kk ? aq1 : aq0;
#pragma unroll
            for (int ni = 0; ni < 4; ++ni) {
                const int row = ni * 16 + l15;
                bf16x8 kf = *(const bf16x8*)(Ks + row * 64 + ((kk * 4 + quad) ^ (row & 7)) * 8);
                st[ni] = MFMA_BF16(kf, aqk, st[ni]);
            }
        }
        // ---- softmax: all 16 j-values belong to THIS lane's q-row ----
        float sv[4][4];
#pragma unroll
        for (int ni = 0; ni < 4; ++ni)
#pragma unroll
            for (int r = 0; r < 4; ++r) {
                const int rel = (j0 + ni * 16 + quad * 4 + r) - i;
                sv[ni][r] = fmaf(st[ni][r], SCALE2, slope2 * (float)rel);
            }
        if (masked) {
#pragma unroll
            for (int ni = 0; ni < 4; ++ni)
#pragma unroll
                for (int r = 0; r < 4; ++r) {
                    const int rel = (j0 + ni * 16 + quad * 4 + r) - i;
                    if (!((unsigned)(-rel) < (unsigned)WIN)) sv[ni][r] = NEGBIG;
                }
        }
        float mx = sv[0][0];
#pragma unroll
        for (int ni = 0; ni < 4; ++ni)
#pragma unroll
            for (int r = 0; r < 4; ++r) mx = fmaxf(mx, sv[ni][r]);
        mx = fmaxf(mx, __shfl_xor(mx, 16));
        mx = fmaxf(mx, __shfl_xor(mx, 32));
        const float mn = fmaxf(m_i, mx);
        const float alpha = exp2f(m_i - mn);
        m_i = mn;
        float pv[4][4];
        float rs = 0.f;
#pragma unroll
        for (int ni = 0; ni < 4; ++ni)
#pragma unroll
            for (int r = 0; r < 4; ++r) {
                pv[ni][r] = exp2f(sv[ni][r] - mn);
                rs += pv[ni][r];
            }
        rs += __shfl_xor(rs, 16);
        rs += __shfl_xor(rs, 32);
        l_i = l_i * alpha + rs;
#pragma unroll
        for (int ni = 0; ni < 4; ++ni)
#pragma unroll
            for (int r = 0; r < 4; ++r) oaccT[ni][r] *= alpha;
        // P fragments: B[k=quad*4+r][n=l15] for j-chunk c == register frag c. No LDS!
        bf16x4 pf[4];
#pragma unroll
        for (int c = 0; c < 4; ++c) pf[c] = pack4(pv[c][0], pv[c][1], pv[c][2], pv[c][3]);
        // ---- O^T += V^T · P : A = V^T[dh=ni*16+l15][j=c*16+quad*4+..] (b64) ----
#pragma unroll
        for (int ni = 0; ni < 4; ++ni) {
            const int row = ni * 16 + l15;
#pragma unroll
            for (int c = 0; c < 4; ++c) {
                const int cj = c * 2 + (quad >> 1);
                bf16x4 vf = *(const bf16x4*)(Vs + row * 64 + ((cj ^ (row & 7)) * 8) +
                                             (quad & 1) * 4);
                oaccT[ni] = MFMA16(vf, pf[c], oaccT[ni]);
            }
        }
    };

    const int jt_lo = (i0 - WIN + 1) > 0 ? ((i0 - WIN + 1) >> 6) : 0;
    int jt = jt_lo;
    stage(jt * 64, K0s, V0s);
    for (;;) {
        __syncthreads();
        if (jt < qt) stage((jt + 1) * 64, K1s, V1s);
        compute(jt * 64, K0s, V0s, (jt == qt) || (qt - jt >= 16));
        if (++jt > qt) break;
        __syncthreads();
        if (jt < qt) stage((jt + 1) * 64, K0s, V0s);
        compute(jt * 64, K1s, V1s, (jt == qt) || (qt - jt >= 16));
        if (++jt > qt) break;
    }
    // epilogue: lane holds q=i; dh = ni*16+quad*4+r (consecutive r -> 8B stores)
    const float inv = 1.0f / l_i;
    __hip_bfloat16* obase = Og + ((size_t)(b * S + i)) * 2048 + h * 64;
#pragma unroll
    for (int ni = 0; ni < 4; ++ni) {
        ushort4 o4 = make_ushort4(f2bfbits(oaccT[ni][0] * inv), f2bfbits(oaccT[ni][1] * inv),
                                  f2bfbits(oaccT[ni][2] * inv), f2bfbits(oaccT[ni][3] * inv));
        *(ushort4*)((ushort_t*)obase + ni * 16 + quad * 4) = o4;
    }
}

// ---------------------------------------------------------------------------
// Fallback attention (round-3 proven; used when ws too small for fast path).
// ---------------------------------------------------------------------------
__global__ __launch_bounds__(256, 2) void attn_kernel(
    const __hip_bfloat16* __restrict__ Qg, const __hip_bfloat16* __restrict__ Kg,
    const __hip_bfloat16* __restrict__ Vg, const float* __restrict__ slopesF,
    __hip_bfloat16* __restrict__ Og) {
    constexpr int S = 2048, WIN = 1024;
    constexpr float SCALE = 0.125f;
    constexpr float LOG2E = 1.44269504f;
    __shared__ __align__(16) ushort_t P_lds[64 * 72];
    __shared__ __align__(16) ushort_t Vts[64 * 72];

    const int tile = blockIdx.x;
    const int qt = tile & 31;
    const int h = (tile >> 5) & 31;
    const int b = tile >> 10;
    const int i0 = qt * 64;
    const int hkv = h >> 2;
    const int tid = threadIdx.x;
    const int wave = tid >> 6, lane = tid & 63;
    const int quad = lane >> 4, l15 = lane & 15;
    const float slope = slopesF[h];

    const int qrow = i0 + wave * 16 + l15;
    const __hip_bfloat16* qbase = Qg + ((size_t)(b * S + qrow)) * 2048 + h * 64;
    bf16x8 aq[2];
    aq[0] = *(const bf16x8*)(qbase + quad * 8);
    aq[1] = *(const bf16x8*)(qbase + 32 + quad * 8);

    f32x4 oacc[4];
#pragma unroll
    for (int ni = 0; ni < 4; ++ni) oacc[ni] = {0.f, 0.f, 0.f, 0.f};
    float m_i[4], l_i[4];
#pragma unroll
    for (int r = 0; r < 4; ++r) { m_i[r] = -1e30f; l_i[r] = 0.f; }

    const int jt_lo = (i0 - WIN + 1) > 0 ? ((i0 - WIN + 1) >> 6) : 0;
    for (int jt = jt_lo; jt <= qt; ++jt) {
        const int j0 = jt * 64;
#pragma unroll
        for (int it = 0; it < 2; ++it) {
            const int j = it * 32 + (tid >> 3);
            const int dh0 = (tid & 7) * 8;
            u16x8 vv = *(const u16x8*)(Vg + ((size_t)(b * S + j0 + j)) * 512 + hkv * 64 + dh0);
#pragma unroll
            for (int e = 0; e < 8; ++e) Vts[(dh0 + e) * 72 + j] = vv[e];
        }
        f32x4 sacc[4];
#pragma unroll
        for (int ni = 0; ni < 4; ++ni) sacc[ni] = {0.f, 0.f, 0.f, 0.f};
#pragma unroll
        for (int kk = 0; kk < 2; ++kk) {
#pragma unroll
            for (int ni = 0; ni < 4; ++ni) {
                bf16x8 bkf = *(const bf16x8*)(Kg + ((size_t)(b * S + j0 + ni * 16 + l15)) * 512 +
                                              hkv * 64 + kk * 32 + quad * 8);
                sacc[ni] = MFMA_BF16(aq[kk], bkf, sacc[ni]);
            }
        }
#pragma unroll
        for (int r = 0; r < 4; ++r) {
            const int i = i0 + wave * 16 + quad * 4 + r;
            float sv[4];
            float rowmax = -1e30f;
#pragma unroll
            for (int ni = 0; ni < 4; ++ni) {
                const int j = j0 + ni * 16 + l15;
                float s = sacc[ni][r] * SCALE + slope * (float)(j - i);
                const bool valid = (j <= i) && ((i - j) < WIN);
                s = valid ? s : -1e30f;
                sv[ni] = s;
                rowmax = fmaxf(rowmax, s);
            }
#pragma unroll
            for (int off = 1; off < 16; off <<= 1)
                rowmax = fmaxf(rowmax, __shfl_xor(rowmax, off));
            const float mn = fmaxf(m_i[r], rowmax);
            const float alpha = exp2f((m_i[r] - mn) * LOG2E);
            float rowsum = 0.f;
#pragma unroll
            for (int ni = 0; ni < 4; ++ni) {
                const float p = (sv[ni] > -1e29f) ? exp2f((sv[ni] - mn) * LOG2E) : 0.f;
                P_lds[(wave * 16 + quad * 4 + r) * 72 + ni * 16 + l15] = f2bfbits(p);
                rowsum += p;
            }
#pragma unroll
            for (int off = 1; off < 16; off <<= 1) rowsum += __shfl_xor(rowsum, off);
            l_i[r] = l_i[r] * alpha + rowsum;
            m_i[r] = mn;
#pragma unroll
            for (int ni = 0; ni < 4; ++ni) oacc[ni][r] *= alpha;
        }
        __syncthreads();
#pragma unroll
        for (int kk = 0; kk < 2; ++kk) {
            bf16x8 ap = *(const bf16x8*)(P_lds + (wave * 16 + l15) * 72 + kk * 32 + quad * 8);
#pragma unroll
            for (int ni = 0; ni < 4; ++ni) {
                bf16x8 bvf = *(const bf16x8*)(Vts + (ni * 16 + l15) * 72 + kk * 32 + quad * 8);
                oacc[ni] = MFMA_BF16(ap, bvf, oacc[ni]);
            }
        }
        __syncthreads();
    }
#pragma unroll
    for (int ni = 0; ni < 4; ++ni) {
#pragma unroll
        for (int r = 0; r < 4; ++r) {
            const int srow = i0 + wave * 16 + quad * 4 + r;
            const float v = oacc[ni][r] / l_i[r];
            Og[((size_t)(b * S + srow)) * 2048 + h * 64 + ni * 16 + l15] = __float2bfloat16(v);
        }
    }
}

extern "C" void kernel_launch(void* const* d_in, const int* in_sizes, int n_in,
                              void* d_out, int out_size, void* d_ws, size_t ws_size,
                              hipStream_t stream) {
    (void)in_sizes; (void)n_in; (void)out_size;
    const void* X  = d_in[0];
    const void* Wq = d_in[1];
    const void* bq = d_in[2];
    const void* Wk = d_in[3];
    const void* bk = d_in[4];
    const void* Wv = d_in[5];
    const void* bv = d_in[6];
    const void* Wo = d_in[7];
    const void* bo = d_in[8];
    const void* sl = d_in[9];
    float* outp = (float*)d_out;

    char* ws = (char*)d_ws;
    const size_t SZ_X  = (size_t)4096 * 2048 * 2;
    const size_t SZ_WQ = (size_t)2048 * 2048 * 2;
    const size_t SZ_WK = (size_t)512 * 2048 * 2;
    const size_t SZ_Q  = SZ_X;
    const size_t SZ_K  = (size_t)4096 * 512 * 2;
    const size_t FAST_NEED = SZ_X + SZ_WQ + 2 * SZ_WK + SZ_Q + 2 * SZ_K + 65536;

    if (ws_size >= FAST_NEED) {
        size_t o = 0;
        __hip_bfloat16* Xb  = (__hip_bfloat16*)(ws + o); o += SZ_X;
        __hip_bfloat16* Wqb = (__hip_bfloat16*)(ws + o); o += SZ_WQ;
        __hip_bfloat16* Wkb = (__hip_bfloat16*)(ws + o); o += SZ_WK;
        __hip_bfloat16* Wvb = (__hip_bfloat16*)(ws + o); o += SZ_WK;
        __hip_bfloat16* Qb  = (__hip_bfloat16*)(ws + o); o += SZ_Q;
        __hip_bfloat16* Kb  = (__hip_bfloat16*)(ws + o); o += SZ_K;
        __hip_bfloat16* Vb  = (__hip_bfloat16*)(ws + o); o += SZ_K;
        __hip_bfloat16* Ab  = Xb;             // X dead after qkv_fast
        __hip_bfloat16* Wob = Wqb;            // Wq dead after qkv_fast
        ushort_t*       Vtg = (ushort_t*)Wkb; // Wk/Wv dead after qkv_fast
        int*   flag    = (int*)(ws + o);
        float* slopesF = (float*)(ws + o + 1024);
        float* bqF     = (float*)(ws + o + 4096);
        float* bkF     = bqF + 2048;
        float* bvF     = bkF + 512;
        float* boF     = bvF + 512;

        detect_kernel<<<1, 256, 0, stream>>>((const ushort_t*)X, bq, bk, bv, bo, sl,
                                             flag, slopesF, bqF, bkF, bvF, boF);
        cvt_kernel<<<2048, 256, 0, stream>>>(flag, X,  (ushort_t*)Xb,  4096 * 2048 / 4);
        cvt_kernel<<<2048, 256, 0, stream>>>(flag, Wq, (ushort_t*)Wqb, 2048 * 2048 / 4);
        cvt_kernel<<<512,  256, 0, stream>>>(flag, Wk, (ushort_t*)Wkb, 512 * 2048 / 4);
        cvt_kernel<<<512,  256, 0, stream>>>(flag, Wv, (ushort_t*)Wvb, 512 * 2048 / 4);
        qkv_fast<<<dim3(24, 32), 256, 0, stream>>>(Xb, Wqb, Wkb, Wvb, bqF, bkF, bvF,
                                                   Qb, Kb, Vb);
        vtrans_kernel<<<1024, 256, 0, stream>>>((const ushort_t*)Vb, Vtg);
        cvt_kernel<<<2048, 256, 0, stream>>>(flag, Wo, (ushort_t*)Wob, 2048 * 2048 / 4);
        attn4_kernel<<<dim3(2048), 256, 0, stream>>>(Qb, Kb, Vtg, slopesF, Ab);
        oproj_fast<<<dim3(16, 32), 256, 0, stream>>>(Ab, Wob, boF, outp);
    } else {
        const size_t MB = 1024 * 1024;
        __hip_bfloat16* Qb = (__hip_bfloat16*)(ws);
        __hip_bfloat16* Kb = (__hip_bfloat16*)(ws + 16 * MB);
        __hip_bfloat16* Vb = (__hip_bfloat16*)(ws + 20 * MB);
        __hip_bfloat16* Ab = (__hip_bfloat16*)(ws + 24 * MB);
        int*   flag    = (int*)(ws + 40 * MB);
        float* slopesF = (float*)(ws + 40 * MB + 1024);
        float* bqF     = (float*)(ws + 40 * MB + 4096);
        float* bkF     = bqF + 2048;
        float* bvF     = bkF + 512;
        float* boF     = bvF + 512;

        detect_kernel<<<1, 256, 0, stream>>>((const ushort_t*)X, bq, bk, bv, bo, sl,
                                             flag, slopesF, bqF, bkF, bvF, boF);
        qkv_kernel<false><<<dim3(24, 32), 256, 0, stream>>>(flag, X, Wq, Wk, Wv,
                                                            bqF, bkF, bvF, Qb, Kb, Vb);
        qkv_kernel<true><<<dim3(24, 32), 256, 0, stream>>>(flag, X, Wq, Wk, Wv,
                                                           bqF, bkF, bvF, Qb, Kb, Vb);
        attn_kernel<<<dim3(2048), 256, 0, stream>>>(Qb, Kb, Vb, slopesF, Ab);
        oproj_kernel<false><<<dim3(16, 32), 256, 0, stream>>>(flag, Ab, Wo, boF, outp);
        oproj_kernel<true><<<dim3(16, 32), 256, 0, stream>>>(flag, Ab, Wo, boF, outp);
    }
}